// Round 12
// baseline (69.069 us; speedup 1.0000x reference)
//
#include <hip/hip_runtime.h>

// Signature-kernel MMD, fused. R23 = R22 (68.20us reproduced; R19-equal) +
// ONE delta: PSUB reassociation to cut the per-substep dependency chain
// from 3 VALU levels (dpp -> pk_add -> pk_fma) to 2 ({pk_fma || dpp} ->
// pk_add). pk_fma now depends only on prev substep's P, so the dpp runs in
// parallel. Same instruction count; values identical modulo ONE reassociated
// add per cell (<=1 ulp/step). DISCRIMINATING TEST: absolute VALU-busy is
// ~9us (R20/R21 profiles) vs ~20-24us sigpde wall -> 40% duty despite 3
// waves/SIMD. If chain-latency-bound with phase-locked waves, this pays
// -2..-5us; if issue-bound, neutral -> ROOFLINE next.
// Session ledger: R20 coop-launch +140us REJECTED; R21 ticket-fence +41us
// REJECTED (cross-block sync >> kernel launch; two-dispatch is optimal).
// Only direct VALU-cycle removal has paid (R14/R16/R17/R18 = -6.3us).

constexpr int PAD2 = 128;   // front pad bytes
constexpr int BNA  = 4800;  // per-pair buffer in fp16 elems (9600 B, 16B-mult)

// write byte offset of (row r, col c=lane): 128 + 146r + A(r) + 2c
#define WOFF(r) (PAD2 + 146 * (r) + ((((r) >> 3) & 7) << 4))

typedef float f32x2 __attribute__((ext_vector_type(2)));

__device__ __forceinline__ float dpp_shr1(float v) {
    // result[l] = src[l-1], result[0] = 0   (wave_shr:1)
    return __builtin_bit_cast(float,
        __builtin_amdgcn_update_dpp(0, __builtin_bit_cast(int, v), 0x138, 0xF, 0xF, true));
}
__device__ __forceinline__ float dpp_shl1(float v) {
    // result[l] = src[l+1], result[63] = 0  (wave_shl:1)
    return __builtin_bit_cast(float,
        __builtin_amdgcn_update_dpp(0, __builtin_bit_cast(int, v), 0x130, 0xF, 0xF, true));
}
__device__ __forceinline__ float dot4(float4 a, float4 b) {
    return a.x * b.x + a.y * b.y + a.z * b.z + a.w * b.w;
}
// Convert-and-fold from packed u32: (float)f16 * 0.25 - 1.0. Exact.
__device__ __forceinline__ float cvtLO(unsigned u, float q25) {
    float r;
    asm("v_fma_mix_f32 %0, %1, %2, -1.0 op_sel_hi:[1,0,0]"
        : "=v"(r) : "v"(u), "s"(q25));
    return r;
}
__device__ __forceinline__ float cvtHI(unsigned u, float q25) {
    float r;
    asm("v_fma_mix_f32 %0, %1, %2, -1.0 op_sel:[1,0,0] op_sel_hi:[1,0,0]"
        : "=v"(r) : "v"(u), "s"(q25));
    return r;
}
// Packed FP32 (CDNA4: half-rate issue, verified R19-neutral vs scalar).
__device__ __forceinline__ f32x2 pk_add(f32x2 a, f32x2 b) {
    f32x2 r;
    asm("v_pk_add_f32 %0, %1, %2" : "=v"(r) : "v"(a), "v"(b));
    return r;
}
__device__ __forceinline__ f32x2 pk_fma(f32x2 a, f32x2 b, f32x2 c) {
    f32x2 r;
    asm("v_pk_fma_f32 %0, %1, %2, %3" : "=v"(r) : "v"(a), "v"(b), "v"(c));
    return r;
}

// One PDE substep (one antidiagonal), packed, chain-shortened (R23):
//   cE = (up2*eF + p1E) + up1;  cO = (p2E*oF + p1O) + p1E
// (reassociated from R3/R6's (up1+p1E)+up2*eF — same sums, <=1ulp/step).
// pk_fma(U,F,P) depends only on prev P; dpp runs in parallel; pk_add joins.
#define PSUB {                                  \
    f32x2 W;                                    \
    W.x = dpp_shr1(P.y);                        \
    W.y = P.x;                                  \
    P = pk_add(pk_fma(U, F, P), W);             \
    U = W; }

// One body = diagonals 2k-1, 2k. cvtexpr supplies of(k) = 0.25*binc - 1.
#define PBODYv(cvtexpr) {                       \
    F.x = dpp_shr1(F.y);                        \
    PSUB                                        \
    F.y = (cvtexpr);                            \
    PSUB }

// 8 bodies off one uint4 chunk (slots x.lo, x.hi, y.lo, y.hi, z.lo, ...).
#define PBODY8(ch) {                                     \
    PBODYv(cvtLO(ch.x, q25)) PBODYv(cvtHI(ch.x, q25))    \
    PBODYv(cvtLO(ch.y, q25)) PBODYv(cvtHI(ch.y, q25))    \
    PBODYv(cvtLO(ch.z, q25)) PBODYv(cvtHI(ch.z, q25))    \
    PBODYv(cvtLO(ch.w, q25)) PBODYv(cvtHI(ch.w, q25)) }

__global__ __launch_bounds__(256, 3) void sigpde_kernel(const float* __restrict__ x,
                                                        const float* __restrict__ y,
                                                        float* __restrict__ pws) {
    __shared__ __align__(16) _Float16 binc[4][BNA];   // 38400 B
    __shared__ float4 xs[4][64];                      //  4096 B
    __shared__ float  xxs[4][64];                     //  1024 B

    const int lane = threadIdx.x & 63;
    const int wid  = threadIdx.x >> 6;
    const int p = blockIdx.x * 4 + wid;     // 0..3071
    const int g = p >> 10;                  // 0: xx, 1: xy, 2: yy
    const int q = p & 1023;
    const int a = q >> 5, b = q & 31;
    const float* Ab = (g == 2) ? y : x;
    const float* Bb = (g == 0) ? x : y;

    _Float16* bw = &binc[wid][0];

    const float C   = -0.72134752044448170f;  // -0.5*log2(e)
    const float L2E =  1.44269504088896340f;  // log2(e) = -2*C

    float4 xa = ((const float4*)(Ab + a * 256))[lane];
    float4 yv = ((const float4*)(Bb + b * 256))[lane];
    xs[wid][lane]  = xa;
    xxs[wid][lane] = C * dot4(xa, xa);        // pre-scaled by C
    const float cyy = C * dot4(yv, yv);       // lane-constant, pre-scaled

    {   // zero this wave's buffer (pads/gaps/overreads must be finite)
        uint4* z = (uint4*)bw;
        const uint4 zz = {0u, 0u, 0u, 0u};
        #pragma unroll
        for (int j = 0; j < 9; ++j) z[lane + 64 * j] = zz;  // 576 of 600
        if (lane < 24) z[576 + lane] = zz;                   // tail
    }
    // No barrier anywhere: all LDS is wave-private; same-wave ds ordering
    // is guaranteed via lgkmcnt.

    // De-phase the 3 co-resident blocks per CU (one-time, <=1280 cyc).
    {
        const int ph = blockIdx.x % 3;
        if (ph == 1)      __builtin_amdgcn_s_sleep(10);  // ~640 cyc
        else if (ph == 2) __builtin_amdgcn_s_sleep(20);  // ~1280 cyc
    }

    // Gram + double increments (column = lane), verified R6/R16:
    // gv = exp2(fma(xy, log2e, cxx+cyy)); store RAW (d - dp) fp16 at the
    // skewed row offset WOFF(u-1) + 2*lane (compile-time per u).
    char* bwh = (char*)bw + 2 * lane;
    float dp;
    {   // peeled u = 0
        float4 x0 = xs[wid][0];
        float g0 = __builtin_amdgcn_exp2f(
            __builtin_fmaf(dot4(x0, yv), L2E, xxs[wid][0] + cyy));
        dp = dpp_shl1(g0) - g0;
    }
    #pragma unroll
    for (int u = 1; u < 64; ++u) {
        float4 xu = xs[wid][u];            // broadcast read
        float gv = __builtin_amdgcn_exp2f(
            __builtin_fmaf(dot4(xu, yv), L2E, xxs[wid][u] + cyy));
        float d = dpp_shl1(gv) - gv;
        *(_Float16*)(bwh + WOFF(u - 1)) = (_Float16)(d - dp);
        dp = d;
    }

    // Goursat PDE: lane owns rows iE=2l, iO=2l+1; body k = diags 2k-1,2k.
    // Lane l's factor stream = row l of binc, read as b128 chunks of 8 fp16
    // at base 128 + 144*lane + A(lane) (16B-aligned, bank-skewed).
    const char* oaB = (const char*)bw + (PAD2 + 144 * lane + (((lane >> 3) & 7) << 4));
    const float q25 = 0.25f;                // SGPR for v_fma_mix

    f32x2 P = { (lane == 0) ? 1.0f : 0.0f, 0.0f };  // (p1E, p1O); K[0,0]=1
    f32x2 U = { 0.0f, 0.0f };                        // (up2, p2E)
    f32x2 F = { -1.0f, -1.0f };                      // F.y = oF(0) = -1

    // 3 chunks in flight (load-to-use distance = 2 full chunk-iterations).
    uint4 cA = *(const uint4*)(oaB +  0);
    uint4 cB = *(const uint4*)(oaB + 16);
    uint4 cC = *(const uint4*)(oaB + 32);

    #pragma unroll
    for (int c = 0; c < 15; ++c) {
        // consume chunk c: bodies 8c+1 .. 8c+8
        PBODY8(cA)
        // rotate + prefetch chunk c+3 (chunks 0..15 cover oA[0..127])
        cA = cB; cB = cC;
        if (c <= 12) cC = *(const uint4*)(oaB + 16 * (c + 3));
    }
    // tail: bodies 121..126 from chunk 15 (slots x.lo .. z.hi)
    PBODYv(cvtLO(cA.x, q25)) PBODYv(cvtHI(cA.x, q25))
    PBODYv(cvtLO(cA.y, q25)) PBODYv(cvtHI(cA.y, q25))
    PBODYv(cvtLO(cA.z, q25)) PBODYv(cvtHI(cA.z, q25))

    // K[126,126] = lane 63's E slot after diagonal 252. Plain store, no atomic.
    if (lane == 63) {
        float w = (g == 1) ? (-2.0f / 1024.0f) : (1.0f / 1024.0f);
        pws[p] = w * P.x;
    }
}

__global__ __launch_bounds__(256) void reduce_kernel(const float* __restrict__ pws,
                                                     float* __restrict__ out) {
    // Sum 3072 weighted partials (768 float4 loads), write out[0].
    float s = 0.0f;
    const float4* v = (const float4*)pws;
    for (int i = threadIdx.x; i < 768; i += 256) {
        float4 t = v[i];
        s += (t.x + t.y) + (t.z + t.w);
    }
    for (int off = 32; off > 0; off >>= 1) s += __shfl_down(s, off);
    __shared__ float ws[4];
    if ((threadIdx.x & 63) == 0) ws[threadIdx.x >> 6] = s;
    __syncthreads();
    if (threadIdx.x == 0) out[0] = (ws[0] + ws[1]) + (ws[2] + ws[3]);
}

extern "C" void kernel_launch(void* const* d_in, const int* in_sizes, int n_in,
                              void* d_out, int out_size, void* d_ws, size_t ws_size,
                              hipStream_t stream) {
    const float* x = (const float*)d_in[0];
    const float* y = (const float*)d_in[1];
    float* out = (float*)d_out;
    float* pws = (float*)d_ws;    // 3072 floats = 12 KB << ws_size
    (void)in_sizes; (void)n_in; (void)out_size; (void)ws_size;

    hipLaunchKernelGGL(sigpde_kernel, dim3(768), dim3(256), 0, stream, x, y, pws);
    hipLaunchKernelGGL(reduce_kernel, dim3(1), dim3(256), 0, stream, pws, out);
}

// Round 13
// 68.088 us; speedup vs baseline: 1.0144x; 1.0144x over previous
//
#include <hip/hip_runtime.h>

// Signature-kernel MMD, fused. R24 = FINAL: pure revert to R19/R22
// (68.14 / 68.20us, twice verified). Session ledger:
//  PAID  (VALU-cycle removal only): R14 strength-reduce -2.6; R16 exp/0.25
//        folds -0.6; R17 fma_mix+unroll -1.8; R18 b128 O-stream -1.3.
//  DEAD: R15 prefetch-depth +2.9 (not LDS-latency-bound); R19 pk-f32
//        neutral (pk is half-rate on CDNA4); R20 coop-launch +140 (runtime
//        grid-sync spin); R21 ticket-fence +41 (device-fence L2 wb/inv per
//        block; cross-block sync >> kernel launch); R23 chain-shortening
//        +0.9 (NOT chain-latency-bound -> issue-bound confirmed).
// Structural floor: 39.4us harness poison-fill (85% HBM) + ~23us sigpde
// (issue-bound; PDE ~2 VALU/cell + 1 DPP/2cells = serial-recurrence
// minimum; Gram 1 exp2+1 fma+1 dpp+1 store per required entry; MFMA
// inapplicable) + ~5us reduce+launch gaps (fusion measured worse twice).
// SQ_LDS_BANK_CONFLICT = 8cyc x 16 b128 = intrinsic wave64 serialization.

constexpr int PAD2 = 128;   // front pad bytes
constexpr int BNA  = 4800;  // per-pair buffer in fp16 elems (9600 B, 16B-mult)

// write byte offset of (row r, col c=lane): 128 + 146r + A(r) + 2c
#define WOFF(r) (PAD2 + 146 * (r) + ((((r) >> 3) & 7) << 4))

typedef float f32x2 __attribute__((ext_vector_type(2)));

__device__ __forceinline__ float dpp_shr1(float v) {
    // result[l] = src[l-1], result[0] = 0   (wave_shr:1)
    return __builtin_bit_cast(float,
        __builtin_amdgcn_update_dpp(0, __builtin_bit_cast(int, v), 0x138, 0xF, 0xF, true));
}
__device__ __forceinline__ float dpp_shl1(float v) {
    // result[l] = src[l+1], result[63] = 0  (wave_shl:1)
    return __builtin_bit_cast(float,
        __builtin_amdgcn_update_dpp(0, __builtin_bit_cast(int, v), 0x130, 0xF, 0xF, true));
}
__device__ __forceinline__ float dot4(float4 a, float4 b) {
    return a.x * b.x + a.y * b.y + a.z * b.z + a.w * b.w;
}
// Convert-and-fold from packed u32: (float)f16 * 0.25 - 1.0. Exact.
__device__ __forceinline__ float cvtLO(unsigned u, float q25) {
    float r;
    asm("v_fma_mix_f32 %0, %1, %2, -1.0 op_sel_hi:[1,0,0]"
        : "=v"(r) : "v"(u), "s"(q25));
    return r;
}
__device__ __forceinline__ float cvtHI(unsigned u, float q25) {
    float r;
    asm("v_fma_mix_f32 %0, %1, %2, -1.0 op_sel:[1,0,0] op_sel_hi:[1,0,0]"
        : "=v"(r) : "v"(u), "s"(q25));
    return r;
}
// Packed FP32 (CDNA4: half-rate issue, verified R19-neutral vs scalar).
__device__ __forceinline__ f32x2 pk_add(f32x2 a, f32x2 b) {
    f32x2 r;
    asm("v_pk_add_f32 %0, %1, %2" : "=v"(r) : "v"(a), "v"(b));
    return r;
}
__device__ __forceinline__ f32x2 pk_fma(f32x2 a, f32x2 b, f32x2 c) {
    f32x2 r;
    asm("v_pk_fma_f32 %0, %1, %2, %3" : "=v"(r) : "v"(a), "v"(b), "v"(c));
    return r;
}

// One PDE substep (one antidiagonal), packed. Scalar-equivalent (verified
// R3/R6 structure): cE = up1 + p1E + up2*eF; cO = p1E + p1O + p2E*oF.
#define PSUB {                                  \
    f32x2 W;                                    \
    W.x = dpp_shr1(P.y);                        \
    W.y = P.x;                                  \
    P = pk_fma(U, F, pk_add(W, P));             \
    U = W; }

// One body = diagonals 2k-1, 2k. cvtexpr supplies of(k) = 0.25*binc - 1.
#define PBODYv(cvtexpr) {                       \
    F.x = dpp_shr1(F.y);                        \
    PSUB                                        \
    F.y = (cvtexpr);                            \
    PSUB }

// 8 bodies off one uint4 chunk (slots x.lo, x.hi, y.lo, y.hi, z.lo, ...).
#define PBODY8(ch) {                                     \
    PBODYv(cvtLO(ch.x, q25)) PBODYv(cvtHI(ch.x, q25))    \
    PBODYv(cvtLO(ch.y, q25)) PBODYv(cvtHI(ch.y, q25))    \
    PBODYv(cvtLO(ch.z, q25)) PBODYv(cvtHI(ch.z, q25))    \
    PBODYv(cvtLO(ch.w, q25)) PBODYv(cvtHI(ch.w, q25)) }

__global__ __launch_bounds__(256, 3) void sigpde_kernel(const float* __restrict__ x,
                                                        const float* __restrict__ y,
                                                        float* __restrict__ pws) {
    __shared__ __align__(16) _Float16 binc[4][BNA];   // 38400 B
    __shared__ float4 xs[4][64];                      //  4096 B
    __shared__ float  xxs[4][64];                     //  1024 B

    const int lane = threadIdx.x & 63;
    const int wid  = threadIdx.x >> 6;
    const int p = blockIdx.x * 4 + wid;     // 0..3071
    const int g = p >> 10;                  // 0: xx, 1: xy, 2: yy
    const int q = p & 1023;
    const int a = q >> 5, b = q & 31;
    const float* Ab = (g == 2) ? y : x;
    const float* Bb = (g == 0) ? x : y;

    _Float16* bw = &binc[wid][0];

    const float C   = -0.72134752044448170f;  // -0.5*log2(e)
    const float L2E =  1.44269504088896340f;  // log2(e) = -2*C

    float4 xa = ((const float4*)(Ab + a * 256))[lane];
    float4 yv = ((const float4*)(Bb + b * 256))[lane];
    xs[wid][lane]  = xa;
    xxs[wid][lane] = C * dot4(xa, xa);        // pre-scaled by C
    const float cyy = C * dot4(yv, yv);       // lane-constant, pre-scaled

    {   // zero this wave's buffer (pads/gaps/overreads must be finite)
        uint4* z = (uint4*)bw;
        const uint4 zz = {0u, 0u, 0u, 0u};
        #pragma unroll
        for (int j = 0; j < 9; ++j) z[lane + 64 * j] = zz;  // 576 of 600
        if (lane < 24) z[576 + lane] = zz;                   // tail
    }
    // No barrier anywhere: all LDS is wave-private; same-wave ds ordering
    // is guaranteed via lgkmcnt.

    // De-phase the 3 co-resident blocks per CU (one-time, <=1280 cyc).
    {
        const int ph = blockIdx.x % 3;
        if (ph == 1)      __builtin_amdgcn_s_sleep(10);  // ~640 cyc
        else if (ph == 2) __builtin_amdgcn_s_sleep(20);  // ~1280 cyc
    }

    // Gram + double increments (column = lane), verified R6/R16:
    // gv = exp2(fma(xy, log2e, cxx+cyy)); store RAW (d - dp) fp16 at the
    // skewed row offset WOFF(u-1) + 2*lane (compile-time per u).
    char* bwh = (char*)bw + 2 * lane;
    float dp;
    {   // peeled u = 0
        float4 x0 = xs[wid][0];
        float g0 = __builtin_amdgcn_exp2f(
            __builtin_fmaf(dot4(x0, yv), L2E, xxs[wid][0] + cyy));
        dp = dpp_shl1(g0) - g0;
    }
    #pragma unroll
    for (int u = 1; u < 64; ++u) {
        float4 xu = xs[wid][u];            // broadcast read
        float gv = __builtin_amdgcn_exp2f(
            __builtin_fmaf(dot4(xu, yv), L2E, xxs[wid][u] + cyy));
        float d = dpp_shl1(gv) - gv;
        *(_Float16*)(bwh + WOFF(u - 1)) = (_Float16)(d - dp);
        dp = d;
    }

    // Goursat PDE: lane owns rows iE=2l, iO=2l+1; body k = diags 2k-1,2k.
    // Lane l's factor stream = row l of binc, read as b128 chunks of 8 fp16
    // at base 128 + 144*lane + A(lane) (16B-aligned, bank-skewed).
    const char* oaB = (const char*)bw + (PAD2 + 144 * lane + (((lane >> 3) & 7) << 4));
    const float q25 = 0.25f;                // SGPR for v_fma_mix

    f32x2 P = { (lane == 0) ? 1.0f : 0.0f, 0.0f };  // (p1E, p1O); K[0,0]=1
    f32x2 U = { 0.0f, 0.0f };                        // (up2, p2E)
    f32x2 F = { -1.0f, -1.0f };                      // F.y = oF(0) = -1

    // 3 chunks in flight (load-to-use distance = 2 full chunk-iterations).
    uint4 cA = *(const uint4*)(oaB +  0);
    uint4 cB = *(const uint4*)(oaB + 16);
    uint4 cC = *(const uint4*)(oaB + 32);

    #pragma unroll
    for (int c = 0; c < 15; ++c) {
        // consume chunk c: bodies 8c+1 .. 8c+8
        PBODY8(cA)
        // rotate + prefetch chunk c+3 (chunks 0..15 cover oA[0..127])
        cA = cB; cB = cC;
        if (c <= 12) cC = *(const uint4*)(oaB + 16 * (c + 3));
    }
    // tail: bodies 121..126 from chunk 15 (slots x.lo .. z.hi)
    PBODYv(cvtLO(cA.x, q25)) PBODYv(cvtHI(cA.x, q25))
    PBODYv(cvtLO(cA.y, q25)) PBODYv(cvtHI(cA.y, q25))
    PBODYv(cvtLO(cA.z, q25)) PBODYv(cvtHI(cA.z, q25))

    // K[126,126] = lane 63's E slot after diagonal 252. Plain store, no atomic.
    if (lane == 63) {
        float w = (g == 1) ? (-2.0f / 1024.0f) : (1.0f / 1024.0f);
        pws[p] = w * P.x;
    }
}

__global__ __launch_bounds__(256) void reduce_kernel(const float* __restrict__ pws,
                                                     float* __restrict__ out) {
    // Sum 3072 weighted partials (768 float4 loads), write out[0].
    float s = 0.0f;
    const float4* v = (const float4*)pws;
    for (int i = threadIdx.x; i < 768; i += 256) {
        float4 t = v[i];
        s += (t.x + t.y) + (t.z + t.w);
    }
    for (int off = 32; off > 0; off >>= 1) s += __shfl_down(s, off);
    __shared__ float ws[4];
    if ((threadIdx.x & 63) == 0) ws[threadIdx.x >> 6] = s;
    __syncthreads();
    if (threadIdx.x == 0) out[0] = (ws[0] + ws[1]) + (ws[2] + ws[3]);
}

extern "C" void kernel_launch(void* const* d_in, const int* in_sizes, int n_in,
                              void* d_out, int out_size, void* d_ws, size_t ws_size,
                              hipStream_t stream) {
    const float* x = (const float*)d_in[0];
    const float* y = (const float*)d_in[1];
    float* out = (float*)d_out;
    float* pws = (float*)d_ws;    // 3072 floats = 12 KB << ws_size
    (void)in_sizes; (void)n_in; (void)out_size; (void)ws_size;

    hipLaunchKernelGGL(sigpde_kernel, dim3(768), dim3(256), 0, stream, x, y, pws);
    hipLaunchKernelGGL(reduce_kernel, dim3(1), dim3(256), 0, stream, pws, out);
}